// Round 1
// baseline (753.702 us; speedup 1.0000x reference)
//
#include <hip/hip_runtime.h>

#define TT 256
#define OBS 96
#define ACTD 32
#define RPB 4      // batch rows per block; grid = 512 -> 2 blocks/CU (LDS ~61KB)
#define CH 8       // steps per x-chunk / z_x burst
#define XCS 144    // xchunk row stride (u16): 288B = 72 words == 8 mod 32 -> 2-way max
#define ZXS 8      // z_xT row-dim (4 valid + 4 pad; 16B col stride)
#define ZBS 69     // zbuf col stride (f32), odd -> spread banks
#define HBS 80     // hbuf row stride (u16): 160B = 40 words == 8 mod 32 -> 2-way max
#define EPS 1e-12f

typedef _Float16 f16x8 __attribute__((ext_vector_type(8)));
typedef float f32x4 __attribute__((ext_vector_type(4)));
typedef unsigned short u16x8 __attribute__((ext_vector_type(8)));
typedef unsigned int u32;
typedef unsigned short u16;

__device__ __forceinline__ u16 f2h(float f) {            // fp32 -> fp16 RNE
  return __builtin_bit_cast(u16, (_Float16)f);
}
__device__ __forceinline__ u32 pk2h(float a, float b) {
  return (u32)f2h(a) | ((u32)f2h(b) << 16);
}
__device__ __forceinline__ float h2f_lo(u32 v) {
  return (float)__builtin_bit_cast(_Float16, (u16)(v & 0xffffu));
}
__device__ __forceinline__ float h2f_hi(u32 v) {
  return (float)__builtin_bit_cast(_Float16, (u16)(v >> 16));
}
__device__ __forceinline__ float sigm(float x) { return 1.0f / (1.0f + __expf(-x)); }
__device__ __forceinline__ float tanh_(float x) { return 1.0f - 2.0f / (__expf(2.0f * x) + 1.0f); }

template <int CTRL>
__device__ __forceinline__ float dpp_add(float x) {
  int t = __builtin_amdgcn_update_dpp(0, __builtin_bit_cast(int, x), CTRL, 0xF, 0xF, true);
  return x + __builtin_bit_cast(float, t);
}
__device__ __forceinline__ float red16(float x) {   // sum within 16-lane groups, pure VALU
  x = dpp_add<0xB1>(x);   // quad_perm xor1
  x = dpp_add<0x4E>(x);   // quad_perm xor2
  x = dpp_add<0x124>(x);  // row_ror:4
  x = dpp_add<0x128>(x);  // row_ror:8
  return x;
}
__device__ __forceinline__ float red64(float x) {   // full-wave sum
  x = red16(x);
  x += __shfl_xor(x, 16, 64);
  x += __shfl_xor(x, 32, 64);
  return x;
}

// Block = 4 batch rows x 256 steps, 8 waves; grid = 512 -> 2 independent
// blocks/CU so the two recurrence groups interleave and cover each other's
// barrier/dependency stalls (prev: 1 block/CU, SIMDs idle in lockstep chain).
// Wave w owns z cols [g*64+half*32, +32), g=w&3, half=w>>2. Per-step chain:
// h-only MFMA (K=64, 2-deep) + precomputed z_x (fp16 LDS) + DPP LN partials |
// barrier | LN + gate math at 1 elem/lane on waves 0..3 (row=wave, col=lane) |
// barrier. z_x = x.Wx burst-computed once per 8 steps (off the recurrence chain).
__global__ __launch_bounds__(512, 4) void lstm_fused(
    const float* __restrict__ obss, const float* __restrict__ actions,
    const float* __restrict__ Wm, const float* __restrict__ gamma,
    const float* __restrict__ beta, const float* __restrict__ dWv,
    const float* __restrict__ dbv, float* __restrict__ out)
{
  __shared__ u16 xchunk[CH][RPB][XCS];     // fp16 x, 8 steps           (9216 B)
  __shared__ u16 zxT[CH][256][ZXS];        // fp16 z_x, transposed      (32768 B)
  __shared__ float zbuf[4][16][ZBS];       // full z per gate (rows 4-15 garbage)
  __shared__ float pbuf[4][16][4];         // gate-LN partials: s0,ss0,s1,ss1
  __shared__ u16 hbuf[RPB][HBS];           // fp16 h(t)
  __shared__ float qbuf[CH][RPB];          // q staging

  const int tid = threadIdx.x;
  const int wv = tid >> 6;
  const int ln = tid & 63;
  const int l15 = ln & 15;
  const int quad = ln >> 4;
  const int g = wv & 3;
  const int half = wv >> 2;
  const int n0 = blockIdx.x * RPB;
  const int c0 = g * 64 + half * 32 + l15;  // this lane's z col (nt=0); nt=1 -> c0+16

  for (int i = tid; i < RPB * HBS / 2; i += 512) ((u32*)hbuf)[i] = 0u;  // h(0)=0

  // W B-fragments (fp16): elem j = W[kt*32+quad*8+j][c0 + nt*16]
  u16x8 bw[6][2];
  #pragma unroll
  for (int kt = 0; kt < 6; ++kt)
    #pragma unroll
    for (int nt = 0; nt < 2; ++nt)
      #pragma unroll
      for (int j = 0; j < 8; ++j)
        bw[kt][nt][j] = f2h(Wm[(kt * 32 + quad * 8 + j) * 256 + c0 + nt * 16]);

  // phase-2 per-lane constants (row = wv, col = ln)
  float ggam[4], gbet[4];
  #pragma unroll
  for (int gg = 0; gg < 4; ++gg) {
    ggam[gg] = gamma[gg * 64 + ln];
    gbet[gg] = beta[gg * 64 + ln];
  }
  const float cgam = gamma[4 * 64 + ln], cbet = beta[4 * 64 + ln];
  const float dw = dWv[ln];
  const float bias = dbv[0];

  // x stager: thread -> (srow, slot), slices sp, sp+4
  const int sp = tid >> 7;                 // 0..3
  const int srow = (tid >> 5) & 3;         // 0..3
  const int slot = tid & 31;               // <24: obs float4, else action float4
  const float* obs_p = obss + (size_t)(n0 + srow) * TT * OBS;
  const float* act_p = actions + (size_t)(n0 + srow) * TT * ACTD;

  f32x4 xst[2];
  #pragma unroll
  for (int k = 0; k < 2; ++k) {            // chunk 0 = steps 0..7
    const int s = sp + 4 * k;
    xst[k] = (slot < 24) ? *(const f32x4*)(obs_p + s * OBS + slot * 4)
                         : *(const f32x4*)(act_p + s * ACTD + (slot - 24) * 4);
  }
  #pragma unroll
  for (int k = 0; k < 2; ++k) {
    const int s = sp + 4 * k;
    *(uint2*)&xchunk[s][srow][slot * 4] =
        make_uint2(pk2h(xst[k][0], xst[k][1]), pk2h(xst[k][2], xst[k][3]));
  }

  float creg = 0.0f;                       // c[row=wv][col=ln], waves 0..3
  __syncthreads();

  for (int t = 0; t < TT; ++t) {
    const int tm = t & 7;

    if (tm == 0) {
      if (t > 0 && tid < 32) {             // flush q for steps t-8..t-1
        const int s = tid >> 2, row = tid & 3;
        out[(size_t)(n0 + row) * TT + (t - 8) + s] = qbuf[s][row] + bias;
      }
      #pragma unroll
      for (int k = 0; k < 2; ++k) {        // prefetch next chunk into regs
        int tl = t + 8 + sp + 4 * k; if (tl > TT - 1) tl = TT - 1;
        xst[k] = (slot < 24) ? *(const f32x4*)(obs_p + tl * OBS + slot * 4)
                             : *(const f32x4*)(act_p + tl * ACTD + (slot - 24) * 4);
      }
      // z_x burst for this chunk: wave computes its 2 col-tiles for 8 slices
      #pragma unroll
      for (int s = 0; s < CH; ++s) {
        u16x8 afx[4];
        #pragma unroll
        for (int kt = 0; kt < 4; ++kt)
          afx[kt] = *(const u16x8*)&xchunk[s][l15 & 3][kt * 32 + quad * 8];
        f32x4 ax0 = {0.f, 0.f, 0.f, 0.f}, ax1 = ax0;
        #pragma unroll
        for (int kt = 0; kt < 4; ++kt) {
          ax0 = __builtin_amdgcn_mfma_f32_16x16x32_f16(
              __builtin_bit_cast(f16x8, afx[kt]), __builtin_bit_cast(f16x8, bw[kt][0]), ax0, 0, 0, 0);
          ax1 = __builtin_amdgcn_mfma_f32_16x16x32_f16(
              __builtin_bit_cast(f16x8, afx[kt]), __builtin_bit_cast(f16x8, bw[kt][1]), ax1, 0, 0, 0);
        }
        if (quad == 0) {                   // valid C rows 0..3
          *(uint2*)&zxT[s][c0][0] =
              make_uint2(pk2h(ax0[0], ax0[1]), pk2h(ax0[2], ax0[3]));
          *(uint2*)&zxT[s][c0 + 16][0] =
              make_uint2(pk2h(ax1[0], ax1[1]), pk2h(ax1[2], ax1[3]));
        }
      }
    }

    // ---- phase 1: z = h.Wh (2-deep MFMA) + z_x ----
    const u16x8 afh0 = *(const u16x8*)&hbuf[l15 & 3][quad * 8];
    const u16x8 afh1 = *(const u16x8*)&hbuf[l15 & 3][32 + quad * 8];
    f32x4 acc0 = {0.f, 0.f, 0.f, 0.f}, acc1 = acc0;
    acc0 = __builtin_amdgcn_mfma_f32_16x16x32_f16(
        __builtin_bit_cast(f16x8, afh0), __builtin_bit_cast(f16x8, bw[4][0]), acc0, 0, 0, 0);
    acc1 = __builtin_amdgcn_mfma_f32_16x16x32_f16(
        __builtin_bit_cast(f16x8, afh0), __builtin_bit_cast(f16x8, bw[4][1]), acc1, 0, 0, 0);
    acc0 = __builtin_amdgcn_mfma_f32_16x16x32_f16(
        __builtin_bit_cast(f16x8, afh1), __builtin_bit_cast(f16x8, bw[5][0]), acc0, 0, 0, 0);
    acc1 = __builtin_amdgcn_mfma_f32_16x16x32_f16(
        __builtin_bit_cast(f16x8, afh1), __builtin_bit_cast(f16x8, bw[5][1]), acc1, 0, 0, 0);

    {
      const uint2 zx0 = *(const uint2*)&zxT[tm][c0][0];        // rows 0..3
      const uint2 zx1 = *(const uint2*)&zxT[tm][c0 + 16][0];
      acc0[0] += h2f_lo(zx0.x); acc0[1] += h2f_hi(zx0.x);
      acc0[2] += h2f_lo(zx0.y); acc0[3] += h2f_hi(zx0.y);
      acc1[0] += h2f_lo(zx1.x); acc1[1] += h2f_hi(zx1.x);
      acc1[2] += h2f_lo(zx1.y); acc1[3] += h2f_hi(zx1.y);
    }

    float s[4], ss[4];
    #pragma unroll
    for (int r = 0; r < 4; ++r) {
      s[r]  = red16(acc0[r] + acc1[r]);
      ss[r] = red16(acc0[r] * acc0[r] + acc1[r] * acc1[r]);
    }
    #pragma unroll
    for (int r = 0; r < 4; ++r) {
      zbuf[g][quad * 4 + r][half * 32 + l15]      = acc0[r];
      zbuf[g][quad * 4 + r][half * 32 + 16 + l15] = acc1[r];
    }
    if (l15 < 4) {
      const float sv  = l15 == 0 ? s[0]  : l15 == 1 ? s[1]  : l15 == 2 ? s[2]  : s[3];
      const float ssv = l15 == 0 ? ss[0] : l15 == 1 ? ss[1] : l15 == 2 ? ss[2] : ss[3];
      *(float2*)&pbuf[g][quad * 4 + l15][half * 2] = make_float2(sv, ssv);
    }
    __syncthreads();

    // ---- phase 2: row = wv, col = ln (1 element/lane, waves 0..3) ----
    if (wv < RPB) {
      float zc[4];
      #pragma unroll
      for (int gg = 0; gg < 4; ++gg) {
        const f32x4 p = *(const f32x4*)&pbuf[gg][wv][0];   // s0,ss0,s1,ss1 (broadcast)
        const float mean = (p[0] + p[2]) * (1.0f / 64.0f);
        const float var  = (p[1] + p[3]) * (1.0f / 64.0f) - mean * mean;
        const float rstd = rsqrtf(var + EPS);
        zc[gg] = (zbuf[gg][wv][ln] - mean) * rstd * ggam[gg] + gbet[gg];
      }
      const float nc = creg * sigm(zc[2] + 1.0f) + sigm(zc[0]) * tanh_(zc[1]);
      const float s2  = red64(nc);
      const float ss2 = red64(nc * nc);
      const float mean = s2 * (1.0f / 64.0f);
      const float var  = ss2 * (1.0f / 64.0f) - mean * mean;
      const float rstd = rsqrtf(var + EPS);
      const float cn = (nc - mean) * rstd * cgam + cbet;
      creg = cn;
      const float h = tanh_(cn) * sigm(zc[3]);
      hbuf[wv][ln] = f2h(h);                                // next step's A-input
      const float qp = red64(h * dw);
      if (ln == 0) qbuf[tm][wv] = qp;
    }

    if (tm == 7) {                          // commit prefetched chunk
      #pragma unroll
      for (int k = 0; k < 2; ++k) {
        const int scm = sp + 4 * k;
        *(uint2*)&xchunk[scm][srow][slot * 4] =
            make_uint2(pk2h(xst[k][0], xst[k][1]), pk2h(xst[k][2], xst[k][3]));
      }
    }
    __syncthreads();
  }

  if (tid < 32) {                           // final q flush (steps 248..255)
    const int s = tid >> 2, row = tid & 3;
    out[(size_t)(n0 + row) * TT + 248 + s] = qbuf[s][row] + bias;
  }
}

extern "C" void kernel_launch(void* const* d_in, const int* in_sizes, int n_in,
                              void* d_out, int out_size, void* d_ws, size_t ws_size,
                              hipStream_t stream) {
  const float* obss    = (const float*)d_in[0];
  const float* actions = (const float*)d_in[1];
  const float* Wm      = (const float*)d_in[2];
  const float* gamma   = (const float*)d_in[3];
  const float* beta    = (const float*)d_in[4];
  const float* dWv     = (const float*)d_in[5];
  const float* dbv     = (const float*)d_in[6];
  float* out = (float*)d_out;
  lstm_fused<<<dim3(2048 / RPB), dim3(512), 0, stream>>>(obss, actions, Wm, gamma,
                                                         beta, dWv, dbv, out);
}

// Round 3
// 668.952 us; speedup vs baseline: 1.1267x; 1.1267x over previous
//
#include <hip/hip_runtime.h>

#define TT 256
#define OBS 96
#define ACTD 32
#define RPB 8      // batch rows per block; grid = 256 -> 1 block/CU (r1: RPB=4 regresses, col-work doesn't amortize)
#define CH 8       // steps per x-chunk / z_x burst
#define XCS 136    // xchunk row stride (u16)
#define ZXS 12     // z_xT row-dim in f32 (8 valid + 4 pad; 48B stride, 16B-aligned for b128)
#define ZBS 69     // zbuf col stride (f32), odd -> spread banks
#define HBS 80     // hh row stride (u16): 160B = 40 words == 8 mod 32
#define EPS 1e-12f

typedef _Float16 f16x8 __attribute__((ext_vector_type(8)));
typedef float f32x4 __attribute__((ext_vector_type(4)));
typedef unsigned short u16x8 __attribute__((ext_vector_type(8)));
typedef unsigned int u32;
typedef unsigned short u16;

__device__ __forceinline__ u16 f2h(float f) {            // fp32 -> fp16 RNE
  return __builtin_bit_cast(u16, (_Float16)f);
}
__device__ __forceinline__ u32 pk2h(float a, float b) {
  return (u32)f2h(a) | ((u32)f2h(b) << 16);
}
__device__ __forceinline__ float sigm(float x) { return 1.0f / (1.0f + __expf(-x)); }
__device__ __forceinline__ float tanh_(float x) { return 1.0f - 2.0f / (__expf(2.0f * x) + 1.0f); }

template <int CTRL>
__device__ __forceinline__ float dpp_add(float x) {
  int t = __builtin_amdgcn_update_dpp(0, __builtin_bit_cast(int, x), CTRL, 0xF, 0xF, true);
  return x + __builtin_bit_cast(float, t);
}
__device__ __forceinline__ float red16(float x) {   // sum within 16-lane groups, pure VALU
  x = dpp_add<0xB1>(x);   // quad_perm xor1
  x = dpp_add<0x4E>(x);   // quad_perm xor2
  x = dpp_add<0x124>(x);  // row_ror:4
  x = dpp_add<0x128>(x);  // row_ror:8
  return x;
}
__device__ __forceinline__ float red64(float x) {   // full-wave sum (r0-proven)
  x = red16(x);
  x += __shfl_xor(x, 16, 64);
  x += __shfl_xor(x, 32, 64);
  return x;
}

// Block = 8 batch rows x 256 steps, 8 waves, 1 block/CU. Wave w owns z cols
// [g*64+half*32, +32), g=w&3, half=w>>2. Per-step chain: h-only MFMA (K=64,
// 2-deep, C seeded with f32 z_x from LDS) + DPP LN partials | barrier | LN +
// gate math at 1 elem/lane (row=wave, col=lane) | barrier. z_x = x.Wx burst-
// computed once per 8 steps; q = h.dW also burst-computed from an 8-step h
// history (both off the recurrence chain).
// NOTE r2 post-mortem: permlane*_swap reductions + lgkm-only barriers (bundled
// with these changes) FAILED correctness at 4.2e-2; this version bisects —
// plain __syncthreads + shfl_xor kept until the barrier variant is isolated.
__global__ __launch_bounds__(512, 2) void lstm_fused(
    const float* __restrict__ obss, const float* __restrict__ actions,
    const float* __restrict__ Wm, const float* __restrict__ gamma,
    const float* __restrict__ beta, const float* __restrict__ dWv,
    const float* __restrict__ dbv, float* __restrict__ out)
{
  __shared__ u16 xchunk[CH][RPB][XCS];     // fp16 x, 8 steps           (17408 B)
  __shared__ float zxT[CH][256][ZXS];      // f32 z_x, transposed       (98304 B)
  __shared__ float zbuf[4][16][ZBS];       // full z per gate (rows 8-15 garbage)
  __shared__ float pbuf[4][16][4];         // gate-LN partials: s0,ss0,s1,ss1
  __shared__ u16 hh[CH][RPB][HBS];         // fp16 h history, slice = t&7

  const int tid = threadIdx.x;
  const int wv = tid >> 6;
  const int ln = tid & 63;
  const int l15 = ln & 15;
  const int quad = ln >> 4;
  const int g = wv & 3;
  const int half = wv >> 2;
  const int n0 = blockIdx.x * RPB;
  const int c0 = g * 64 + half * 32 + l15;  // this lane's z col (nt=0); nt=1 -> c0+16

  for (int i = tid; i < CH * RPB * HBS / 2; i += 512) ((u32*)hh)[i] = 0u;  // h<=0 := 0

  // W B-fragments (fp16): elem j = W[kt*32+quad*8+j][c0 + nt*16]
  u16x8 bw[6][2];
  #pragma unroll
  for (int kt = 0; kt < 6; ++kt)
    #pragma unroll
    for (int nt = 0; nt < 2; ++nt)
      #pragma unroll
      for (int j = 0; j < 8; ++j)
        bw[kt][nt][j] = f2h(Wm[(kt * 32 + quad * 8 + j) * 256 + c0 + nt * 16]);

  // phase-2 per-lane constants (row = wv, col = ln)
  float ggam[4], gbet[4];
  #pragma unroll
  for (int gg = 0; gg < 4; ++gg) {
    ggam[gg] = gamma[gg * 64 + ln];
    gbet[gg] = beta[gg * 64 + ln];
  }
  const float cgam = gamma[4 * 64 + ln], cbet = beta[4 * 64 + ln];
  const float dw = dWv[ln];
  const float bias = dbv[0];

  // x stager: thread -> (srow, slot), slices sp, sp+2, sp+4, sp+6
  const int sp = tid >> 8;
  const int srow = (tid >> 5) & 7;
  const int slot = tid & 31;               // <24: obs float4, else action float4
  const float* obs_p = obss + (size_t)(n0 + srow) * TT * OBS;
  const float* act_p = actions + (size_t)(n0 + srow) * TT * ACTD;

  f32x4 xst[4];
  #pragma unroll
  for (int k = 0; k < 4; ++k) {            // chunk 0 = steps 0..7
    const int s = sp + 2 * k;
    xst[k] = (slot < 24) ? *(const f32x4*)(obs_p + s * OBS + slot * 4)
                         : *(const f32x4*)(act_p + s * ACTD + (slot - 24) * 4);
  }
  #pragma unroll
  for (int k = 0; k < 4; ++k) {
    const int s = sp + 2 * k;
    *(uint2*)&xchunk[s][srow][slot * 4] =
        make_uint2(pk2h(xst[k][0], xst[k][1]), pk2h(xst[k][2], xst[k][3]));
  }

  float creg = 0.0f;                       // c[row=wv][col=ln]
  __syncthreads();

  for (int t = 0; t < TT; ++t) {
    const int tm = t & 7;
    const int tp = (t + 7) & 7;            // hh slice holding h(t-1)

    if (tm == 0) {
      if (t > 0) {                         // q for steps t-8..t-1: wave wv = row wv
        #pragma unroll
        for (int s = 0; s < CH; ++s) {
          const float hv = (float)__builtin_bit_cast(_Float16, hh[s][wv][ln]);
          const float qv = red64(hv * dw);
          if (ln == 0) out[(size_t)(n0 + wv) * TT + (t - 8) + s] = qv + bias;
        }
      }
      #pragma unroll
      for (int k = 0; k < 4; ++k) {        // prefetch next chunk into regs
        int tl = t + 8 + sp + 2 * k; if (tl > TT - 1) tl = TT - 1;
        xst[k] = (slot < 24) ? *(const f32x4*)(obs_p + tl * OBS + slot * 4)
                             : *(const f32x4*)(act_p + tl * ACTD + (slot - 24) * 4);
      }
      // z_x burst for this chunk: wave computes its 2 col-tiles for 8 slices
      #pragma unroll
      for (int s = 0; s < CH; ++s) {
        u16x8 afx[4];
        #pragma unroll
        for (int kt = 0; kt < 4; ++kt)
          afx[kt] = *(const u16x8*)&xchunk[s][l15 & 7][kt * 32 + quad * 8];
        f32x4 ax0 = {0.f, 0.f, 0.f, 0.f}, ax1 = ax0;
        #pragma unroll
        for (int kt = 0; kt < 4; ++kt) {
          ax0 = __builtin_amdgcn_mfma_f32_16x16x32_f16(
              __builtin_bit_cast(f16x8, afx[kt]), __builtin_bit_cast(f16x8, bw[kt][0]), ax0, 0, 0, 0);
          ax1 = __builtin_amdgcn_mfma_f32_16x16x32_f16(
              __builtin_bit_cast(f16x8, afx[kt]), __builtin_bit_cast(f16x8, bw[kt][1]), ax1, 0, 0, 0);
        }
        if (quad < 2) {                    // valid C rows 0..7 (quad 0,1)
          *(f32x4*)&zxT[s][c0][quad * 4] = ax0;
          *(f32x4*)&zxT[s][c0 + 16][quad * 4] = ax1;
        }
      }
    }

    // ---- phase 1: z = h.Wh (2-deep MFMA, C seeded with f32 z_x) ----
    const u16x8 afh0 = *(const u16x8*)&hh[tp][l15 & 7][quad * 8];
    const u16x8 afh1 = *(const u16x8*)&hh[tp][l15 & 7][32 + quad * 8];
    const f32x4 zs0 = *(const f32x4*)&zxT[tm][c0][(quad & 1) * 4];
    const f32x4 zs1 = *(const f32x4*)&zxT[tm][c0 + 16][(quad & 1) * 4];
    f32x4 acc0 = __builtin_amdgcn_mfma_f32_16x16x32_f16(
        __builtin_bit_cast(f16x8, afh0), __builtin_bit_cast(f16x8, bw[4][0]), zs0, 0, 0, 0);
    f32x4 acc1 = __builtin_amdgcn_mfma_f32_16x16x32_f16(
        __builtin_bit_cast(f16x8, afh0), __builtin_bit_cast(f16x8, bw[4][1]), zs1, 0, 0, 0);
    acc0 = __builtin_amdgcn_mfma_f32_16x16x32_f16(
        __builtin_bit_cast(f16x8, afh1), __builtin_bit_cast(f16x8, bw[5][0]), acc0, 0, 0, 0);
    acc1 = __builtin_amdgcn_mfma_f32_16x16x32_f16(
        __builtin_bit_cast(f16x8, afh1), __builtin_bit_cast(f16x8, bw[5][1]), acc1, 0, 0, 0);

    float s[4], ss[4];
    #pragma unroll
    for (int r = 0; r < 4; ++r) {
      s[r]  = red16(acc0[r] + acc1[r]);
      ss[r] = red16(acc0[r] * acc0[r] + acc1[r] * acc1[r]);
    }
    #pragma unroll
    for (int r = 0; r < 4; ++r) {
      zbuf[g][quad * 4 + r][half * 32 + l15]      = acc0[r];
      zbuf[g][quad * 4 + r][half * 32 + 16 + l15] = acc1[r];
    }
    if (l15 < 4) {
      const float sv  = l15 == 0 ? s[0]  : l15 == 1 ? s[1]  : l15 == 2 ? s[2]  : s[3];
      const float ssv = l15 == 0 ? ss[0] : l15 == 1 ? ss[1] : l15 == 2 ? ss[2] : ss[3];
      *(float2*)&pbuf[g][quad * 4 + l15][half * 2] = make_float2(sv, ssv);
    }
    __syncthreads();

    // ---- phase 2: row = wv, col = ln (1 element/lane, all 8 waves) ----
    float zc[4];
    #pragma unroll
    for (int gg = 0; gg < 4; ++gg) {
      const f32x4 p = *(const f32x4*)&pbuf[gg][wv][0];   // s0,ss0,s1,ss1 (broadcast)
      const float mean = (p[0] + p[2]) * (1.0f / 64.0f);
      const float var  = (p[1] + p[3]) * (1.0f / 64.0f) - mean * mean;
      const float rstd = rsqrtf(var + EPS);
      zc[gg] = (zbuf[gg][wv][ln] - mean) * rstd * ggam[gg] + gbet[gg];
    }
    const float nc = creg * sigm(zc[2] + 1.0f) + sigm(zc[0]) * tanh_(zc[1]);
    const float s2  = red64(nc);
    const float ss2 = red64(nc * nc);
    const float mean = s2 * (1.0f / 64.0f);
    const float var  = ss2 * (1.0f / 64.0f) - mean * mean;
    const float rstd = rsqrtf(var + EPS);
    const float cn = (nc - mean) * rstd * cgam + cbet;
    creg = cn;
    const float h = tanh_(cn) * sigm(zc[3]);
    hh[tm][wv][ln] = f2h(h);                              // h(t) -> history slice tm

    if (tm == 7) {                          // commit prefetched chunk
      #pragma unroll
      for (int k = 0; k < 4; ++k) {
        const int scm = sp + 2 * k;
        *(uint2*)&xchunk[scm][srow][slot * 4] =
            make_uint2(pk2h(xst[k][0], xst[k][1]), pk2h(xst[k][2], xst[k][3]));
      }
    }
    __syncthreads();
  }

  // final q flush (steps 248..255) from history
  #pragma unroll
  for (int s = 0; s < CH; ++s) {
    const float hv = (float)__builtin_bit_cast(_Float16, hh[s][wv][ln]);
    const float qv = red64(hv * dw);
    if (ln == 0) out[(size_t)(n0 + wv) * TT + 248 + s] = qv + bias;
  }
}

extern "C" void kernel_launch(void* const* d_in, const int* in_sizes, int n_in,
                              void* d_out, int out_size, void* d_ws, size_t ws_size,
                              hipStream_t stream) {
  const float* obss    = (const float*)d_in[0];
  const float* actions = (const float*)d_in[1];
  const float* Wm      = (const float*)d_in[2];
  const float* gamma   = (const float*)d_in[3];
  const float* beta    = (const float*)d_in[4];
  const float* dWv     = (const float*)d_in[5];
  const float* dbv     = (const float*)d_in[6];
  float* out = (float*)d_out;
  lstm_fused<<<dim3(2048 / RPB), dim3(512), 0, stream>>>(obss, actions, Wm, gamma,
                                                         beta, dWv, dbv, out);
}